// Round 12
// baseline (106.592 us; speedup 1.0000x reference)
//
#include <hip/hip_runtime.h>
#include <hip/hip_bf16.h>

#define N_TOK   16384   // B * N_PEP
#define NREC    10
#define EMB     256
#define TWO_EMB 512
#define OUTD    256
#define T_BLK   16      // tokens per block
#define THREADS 512     // 8 waves; wave w owns tokens 2w, 2w+1 in streaming phase

typedef __bf16 bf16x8 __attribute__((ext_vector_type(8)));
typedef float  f32x4  __attribute__((ext_vector_type(4)));

static __device__ __forceinline__ unsigned int f2bf_bits(float f) {
    unsigned int u = __builtin_bit_cast(unsigned int, f);
    u = (u + 0x7fffu + ((u >> 16) & 1u)) >> 16;   // RNE bf16
    return u & 0xffffu;
}
static __device__ __forceinline__ unsigned int pack2(float a, float b) {
    return f2bf_bits(a) | (f2bf_bits(b) << 16);
}
static __device__ __forceinline__ float bflo(unsigned int u) {
    return __builtin_bit_cast(float, u << 16);
}
static __device__ __forceinline__ float bfhi(unsigned int u) {
    return __builtin_bit_cast(float, u & 0xffff0000u);
}

// 64-lane sum: 4 DPP row_ror adds + 2 shuffles (validated spill-free, R8/R11).
static __device__ __forceinline__ float wave_sum(float p) {
    p += __builtin_bit_cast(float, __builtin_amdgcn_update_dpp(
             0, __builtin_bit_cast(int, p), 0x121, 0xf, 0xf, true));   // ror1
    p += __builtin_bit_cast(float, __builtin_amdgcn_update_dpp(
             0, __builtin_bit_cast(int, p), 0x122, 0xf, 0xf, true));   // ror2
    p += __builtin_bit_cast(float, __builtin_amdgcn_update_dpp(
             0, __builtin_bit_cast(int, p), 0x124, 0xf, 0xf, true));   // ror4
    p += __builtin_bit_cast(float, __builtin_amdgcn_update_dpp(
             0, __builtin_bit_cast(int, p), 0x128, 0xf, 0xf, true));   // ror8
    p += __shfl_xor(p, 16);
    p += __shfl_xor(p, 32);
    return p;
}

// ---------- prep 1: M = Wr^T @ Wp  (bf16 B-frag layout) and c = Wr^T @ bp -----
// One block per (nt,kt): nt in [0,32) over d (512), kt in [0,8) over j (256).
__global__ void prep_mfrag(const float* __restrict__ Wr,
                           const float* __restrict__ Wp,
                           const float* __restrict__ Wp_b,
                           short* __restrict__ m_frag,
                           float* __restrict__ c_vec) {
    __shared__ float WrL[256][16];   // Wr[o][n0..n0+15]  (n = d index)
    __shared__ float WpL[256][32];   // Wp[o][k0..k0+31]  (k = j index)
    __shared__ float outL[16][32];
    const int nt = blockIdx.x >> 3, kt = blockIdx.x & 7;
    const int n0 = nt * 16, k0 = kt * 32;
    const int t = threadIdx.x;       // 256 threads; thread t stages row o = t
    {
        const float* wr = Wr + t * TWO_EMB + n0;
        #pragma unroll
        for (int i = 0; i < 16; ++i) WrL[t][i] = wr[i];
        const float* wp = Wp + t * EMB + k0;
        #pragma unroll
        for (int i = 0; i < 32; ++i) WpL[t][i] = wp[i];
    }
    __syncthreads();
    {
        int n = t & 15, kl = t >> 4;
        float acc0 = 0.f, acc1 = 0.f;
        #pragma unroll 4
        for (int o = 0; o < 256; ++o) {
            float w = WrL[o][n];
            acc0 += w * WpL[o][kl];
            acc1 += w * WpL[o][kl + 16];
        }
        outL[n][kl] = acc0;
        outL[n][kl + 16] = acc1;
    }
    if (kt == 0 && t < 16) {
        float acc = 0.f;
        for (int o = 0; o < 256; ++o) acc += WrL[o][t] * Wp_b[o];
        c_vec[n0 + t] = acc;
    }
    __syncthreads();
    for (int idx = t; idx < 512; idx += 256) {
        int lane = idx >> 3, j = idx & 7;
        int n = lane & 15, kl = ((lane >> 4) << 3) + j;
        m_frag[(((nt * 8 + kt) * 64 + lane) << 3) + j] = (short)f2bf_bits(outL[n][kl]);
    }
}

// ---------- prep 2: [Wp | Wv] concat B-frags for the K=768 output GEMM --------
__global__ void prep_wpv(const float* __restrict__ Wp,
                         const float* __restrict__ Wv,
                         short* __restrict__ wpv_frag) {
    int idx = blockIdx.x * blockDim.x + threadIdx.x;   // < 16*24*64*8 = 196608
    if (idx < 16 * 24 * 64 * 8) {
        int j = idx & 7, lane = (idx >> 3) & 63;
        int ntkt = idx >> 9, kt = ntkt % 24, nt = ntkt / 24;
        int n = nt * 16 + (lane & 15);
        int k = kt * 32 + ((lane >> 4) << 3) + j;
        float v = (k < 256) ? Wp[n * EMB + k] : Wv[n * TWO_EMB + (k - 256)];
        wpv_frag[idx] = (short)f2bf_bits(v);
    }
}

// Direct-from-f32 B loaders (fallback path only)
static __device__ __forceinline__ bf16x8 load_b_rm0(const float* __restrict__ W,
                                                    int n, int k, int ld) {
    const float* s = W + (long)n * ld + k;
    float4 f0 = *reinterpret_cast<const float4*>(s);
    float4 f1 = *reinterpret_cast<const float4*>(s + 4);
    uint4 t = { pack2(f0.x, f0.y), pack2(f0.z, f0.w), pack2(f1.x, f1.y), pack2(f1.z, f1.w) };
    return __builtin_bit_cast(bf16x8, t);
}
static __device__ __forceinline__ bf16x8 load_b_tr0(const float* __restrict__ W,
                                                    int n, int k, int ld) {
    unsigned int p[4];
    #pragma unroll
    for (int jj = 0; jj < 4; ++jj)
        p[jj] = pack2(W[(long)(k + 2 * jj) * ld + n], W[(long)(k + 2 * jj + 1) * ld + n]);
    uint4 t = { p[0], p[1], p[2], p[3] };
    return __builtin_bit_cast(bf16x8, t);
}

// ---- one-pass streaming for a token: xbar = (sum e_r x_r) / (sum e_r) --------
static __device__ __forceinline__ void stream_token(
    const float* __restrict__ bp,
    const unsigned char* __restrict__ qrb,
    unsigned char* __restrict__ xz,
    int t, int lane,
    float4 s0l, float4 s0h, float4 s1l, float4 s1h,
    float4 s2l, float4 s2h, float4 s3l, float4 s3h)
{
    uint4 qw = *reinterpret_cast<const uint4*>(qrb + t * 1024 + lane * 16);
    const float qa0 = bflo(qw.x), qa1 = bfhi(qw.x), qa2 = bflo(qw.y), qa3 = bfhi(qw.y);
    const float qa4 = bflo(qw.z), qa5 = bfhi(qw.z), qa6 = bflo(qw.w), qa7 = bfhi(qw.w);
    const float C = 0.0625f * 1.4426950408889634f;   // 1/sqrt(256) * log2(e)

    float s = 0.f;
    float4 xb0 = make_float4(0.f, 0.f, 0.f, 0.f), xb1 = xb0;

    #define LD(r, sl, sh) { sl = *reinterpret_cast<const float4*>(bp + (r) * EMB); \
                            sh = *reinterpret_cast<const float4*>(bp + (r) * EMB + 4); }
    #define PROC(sl, sh) { \
        float p = qa0*(sl).x + qa1*(sl).y + qa2*(sl).z + qa3*(sl).w \
                + qa4*(sh).x + qa5*(sh).y + qa6*(sh).z + qa7*(sh).w; \
        p = wave_sum(p); \
        float e = exp2f(p * C);                      /* no-max: |logit| <~ 2 */ \
        s += e; \
        xb0.x += e*(sl).x; xb0.y += e*(sl).y; xb0.z += e*(sl).z; xb0.w += e*(sl).w; \
        xb1.x += e*(sh).x; xb1.y += e*(sh).y; xb1.z += e*(sh).z; xb1.w += e*(sh).w; }

    PROC(s0l, s0h); LD(4, s0l, s0h);
    PROC(s1l, s1h); LD(5, s1l, s1h);
    PROC(s2l, s2h); LD(6, s2l, s2h);
    PROC(s3l, s3h); LD(7, s3l, s3h);
    PROC(s0l, s0h); LD(8, s0l, s0h);
    PROC(s1l, s1h); LD(9, s1l, s1h);
    PROC(s2l, s2h);
    PROC(s3l, s3h);
    PROC(s0l, s0h);
    PROC(s1l, s1h);
    #undef LD
    #undef PROC

    const float inv = 1.f / s;
    uint4 wv4 = { pack2(xb0.x * inv, xb0.y * inv), pack2(xb0.z * inv, xb0.w * inv),
                  pack2(xb1.x * inv, xb1.y * inv), pack2(xb1.z * inv, xb1.w * inv) };
    *reinterpret_cast<uint4*>(xz + 1024 * t + ((lane * 16) ^ ((t & 7) << 4))) = wv4;
}

// ---------------- main fused kernel (merged-projection formulation) -----------
// qr  = M @ pep + c          (ONE pre-stream GEMM; M = Wr^T Wp precomputed)
// e_r = exp((qr . x_r)/16);  xbar = (sum e_r x_r)/(sum e_r)     (streamed)
// out = [Wp|Wv] @ [pep;xbar] + (bp + bv)                        (K=768 GEMM)
__launch_bounds__(THREADS, 4)
__global__ void ga10_fused(const float* __restrict__ rec,
                           const float* __restrict__ pep,
                           const float* __restrict__ edge,
                           const short* __restrict__ m_frag,
                           const float* __restrict__ c_vec,
                           const short* __restrict__ wpv_frag,
                           const float* __restrict__ Wp_b,
                           const float* __restrict__ Wv_b,
                           float* __restrict__ out) {
    __shared__ __align__(16) unsigned char pepb[T_BLK * 512];    // 8 KB (whole kernel)
    __shared__ __align__(16) unsigned char qrb[T_BLK * 1024];    // 16 KB
    __shared__ __align__(16) unsigned char xz[T_BLK * 1024];     // 16 KB (xbar)

    const int tid  = threadIdx.x;
    const int lane = tid & 63;
    const int wave = tid >> 6;
    const int tok0 = blockIdx.x * T_BLK;

    // ---- stage pep tile as bf16 (swizzled) ----
    #pragma unroll
    for (int it = 0; it < 2; ++it) {
        int idx = tid + it * THREADS;          // 16 rows x 64 float4
        int row = idx >> 6, d4 = (idx & 63) << 2;
        float4 f = *reinterpret_cast<const float4*>(pep + (long)(tok0 + row) * EMB + d4);
        uint2 w = { pack2(f.x, f.y), pack2(f.z, f.w) };
        *reinterpret_cast<uint2*>(pepb + 512 * row + ((d4 * 2) ^ ((row & 7) << 4))) = w;
    }
    __syncthreads();                            // B1: pep tile ready

    // ---- pre-issue token-A rows 0..3; they drain under the qr GEMM ----
    const float* srcA = (lane < 32) ? rec : edge;
    const int dloc = (lane * 8) & 255;
    const float* baseA = srcA + (long)(tok0 + wave * 2) * NREC * EMB + dloc;
    const float* baseB = baseA + (long)NREC * EMB;   // token A+1
    float4 a0l = *reinterpret_cast<const float4*>(baseA + 0 * EMB);
    float4 a0h = *reinterpret_cast<const float4*>(baseA + 0 * EMB + 4);
    float4 a1l = *reinterpret_cast<const float4*>(baseA + 1 * EMB);
    float4 a1h = *reinterpret_cast<const float4*>(baseA + 1 * EMB + 4);
    float4 a2l = *reinterpret_cast<const float4*>(baseA + 2 * EMB);
    float4 a2h = *reinterpret_cast<const float4*>(baseA + 2 * EMB + 4);
    float4 a3l = *reinterpret_cast<const float4*>(baseA + 3 * EMB);
    float4 a3h = *reinterpret_cast<const float4*>(baseA + 3 * EMB + 4);

    // ---- qr = M @ pep + c  (M=16,K=256,N=512; 4 n-tiles/wave), stored bf16 ----
    {
        f32x4 racc[4] = {};
        #pragma unroll
        for (int kt = 0; kt < 8; ++kt) {
            int kk = kt * 32 + ((lane >> 4) << 3);
            int row = lane & 15;
            bf16x8 a = *reinterpret_cast<const bf16x8*>(pepb + 512 * row + ((kk * 2) ^ ((row & 7) << 4)));
            #pragma unroll
            for (int ntl = 0; ntl < 4; ++ntl) {
                int nt = wave * 4 + ntl;
                bf16x8 b = *reinterpret_cast<const bf16x8*>(m_frag + (((nt * 8 + kt) * 64 + lane) << 3));
                racc[ntl] = __builtin_amdgcn_mfma_f32_16x16x32_bf16(a, b, racc[ntl], 0, 0, 0);
            }
        }
        #pragma unroll
        for (int ntl = 0; ntl < 4; ++ntl) {
            int n = (wave * 4 + ntl) * 16 + (lane & 15);
            float cv = c_vec[n];
            #pragma unroll
            for (int i = 0; i < 4; ++i) {
                int row = ((lane >> 4) << 2) + i;
                *reinterpret_cast<unsigned short*>(qrb + row * 1024 + n * 2)
                    = (unsigned short)f2bf_bits(racc[ntl][i] + cv);
            }
        }
    }
    __syncthreads();                            // B2: qrb ready

    // ---- streaming: token A (ring pre-issued), then token B ----
    stream_token(baseA, qrb, xz, wave * 2, lane, a0l, a0h, a1l, a1h, a2l, a2h, a3l, a3h);
    {
        float4 b0l = *reinterpret_cast<const float4*>(baseB + 0 * EMB);
        float4 b0h = *reinterpret_cast<const float4*>(baseB + 0 * EMB + 4);
        float4 b1l = *reinterpret_cast<const float4*>(baseB + 1 * EMB);
        float4 b1h = *reinterpret_cast<const float4*>(baseB + 1 * EMB + 4);
        float4 b2l = *reinterpret_cast<const float4*>(baseB + 2 * EMB);
        float4 b2h = *reinterpret_cast<const float4*>(baseB + 2 * EMB + 4);
        float4 b3l = *reinterpret_cast<const float4*>(baseB + 3 * EMB);
        float4 b3h = *reinterpret_cast<const float4*>(baseB + 3 * EMB + 4);
        stream_token(baseB, qrb, xz, wave * 2 + 1, lane, b0l, b0h, b1l, b1h, b2l, b2h, b3l, b3h);
    }
    __syncthreads();                            // B3: xbar tile ready

    // ---- out = [Wp|Wv] @ [pep;xbar] + (bp+bv)  (M=16,K=768,N=256) ----
    {
        f32x4 oacc[2] = {};
        #pragma unroll
        for (int kt = 0; kt < 24; ++kt) {
            int row = lane & 15;
            bf16x8 a;
            if (kt < 8) {
                int kk = kt * 32 + ((lane >> 4) << 3);
                a = *reinterpret_cast<const bf16x8*>(pepb + 512 * row + ((kk * 2) ^ ((row & 7) << 4)));
            } else {
                int kk = (kt - 8) * 32 + ((lane >> 4) << 3);
                a = *reinterpret_cast<const bf16x8*>(xz + 1024 * row + ((kk * 2) ^ ((row & 7) << 4)));
            }
            #pragma unroll
            for (int ntl = 0; ntl < 2; ++ntl) {
                int nt = wave * 2 + ntl;
                bf16x8 b = *reinterpret_cast<const bf16x8*>(wpv_frag + (((nt * 24 + kt) * 64 + lane) << 3));
                oacc[ntl] = __builtin_amdgcn_mfma_f32_16x16x32_bf16(a, b, oacc[ntl], 0, 0, 0);
            }
        }
        #pragma unroll
        for (int ntl = 0; ntl < 2; ++ntl) {
            int n = (wave * 2 + ntl) * 16 + (lane & 15);
            float bias = Wp_b[n] + Wv_b[n];
            #pragma unroll
            for (int i = 0; i < 4; ++i) {
                int row = ((lane >> 4) << 2) + i;
                out[(long)(tok0 + row) * OUTD + n] = oacc[ntl][i] + bias;
            }
        }
    }
}

// ======================= Fallback (R11 structure, direct W loads) =============
__launch_bounds__(THREADS, 4)
__global__ void ga_fb(const float* __restrict__ rec,
                      const float* __restrict__ pep,
                      const float* __restrict__ edge,
                      const float* __restrict__ Wp_w,
                      const float* __restrict__ Wp_b,
                      const float* __restrict__ Wr_w,
                      const float* __restrict__ Wv_w,
                      const float* __restrict__ Wv_b,
                      float* __restrict__ out) {
    __shared__ __align__(16) unsigned char xz[T_BLK * 1024];
    __shared__ __align__(16) unsigned char qbf[T_BLK * 512];
    __shared__ __align__(16) unsigned char qrb[T_BLK * 1024];

    const int tid  = threadIdx.x;
    const int lane = tid & 63;
    const int wave = tid >> 6;
    const int tok0 = blockIdx.x * T_BLK;

    #pragma unroll
    for (int it = 0; it < 2; ++it) {
        int idx = tid + it * THREADS;
        int row = idx >> 6, d4 = (idx & 63) << 2;
        float4 f = *reinterpret_cast<const float4*>(pep + (long)(tok0 + row) * EMB + d4);
        uint2 w = { pack2(f.x, f.y), pack2(f.z, f.w) };
        *reinterpret_cast<uint2*>(xz + 512 * row + ((d4 * 2) ^ ((row & 7) << 4))) = w;
    }
    __syncthreads();

    {
        f32x4 qacc[2] = {};
        #pragma unroll
        for (int kt = 0; kt < 8; ++kt) {
            int kk = kt * 32 + ((lane >> 4) << 3);
            int row = lane & 15;
            bf16x8 a = *reinterpret_cast<const bf16x8*>(xz + 512 * row + ((kk * 2) ^ ((row & 7) << 4)));
            #pragma unroll
            for (int ntl = 0; ntl < 2; ++ntl) {
                int nt = wave * 2 + ntl;
                bf16x8 b = load_b_rm0(Wp_w, nt * 16 + (lane & 15), kk, EMB);
                qacc[ntl] = __builtin_amdgcn_mfma_f32_16x16x32_bf16(a, b, qacc[ntl], 0, 0, 0);
            }
        }
        #pragma unroll
        for (int ntl = 0; ntl < 2; ++ntl) {
            int n = (wave * 2 + ntl) * 16 + (lane & 15);
            float bias = Wp_b[n];
            #pragma unroll
            for (int i = 0; i < 4; ++i) {
                int row = ((lane >> 4) << 2) + i;
                *reinterpret_cast<unsigned short*>(qbf + 512 * row + ((n * 2) ^ ((row & 7) << 4)))
                    = (unsigned short)f2bf_bits(qacc[ntl][i] + bias);
            }
        }
    }

    const float* srcA = (lane < 32) ? rec : edge;
    const int dloc = (lane * 8) & 255;
    const float* baseA = srcA + (long)(tok0 + wave * 2) * NREC * EMB + dloc;
    const float* baseB = baseA + (long)NREC * EMB;
    float4 a0l = *reinterpret_cast<const float4*>(baseA + 0 * EMB);
    float4 a0h = *reinterpret_cast<const float4*>(baseA + 0 * EMB + 4);
    float4 a1l = *reinterpret_cast<const float4*>(baseA + 1 * EMB);
    float4 a1h = *reinterpret_cast<const float4*>(baseA + 1 * EMB + 4);
    float4 a2l = *reinterpret_cast<const float4*>(baseA + 2 * EMB);
    float4 a2h = *reinterpret_cast<const float4*>(baseA + 2 * EMB + 4);
    float4 a3l = *reinterpret_cast<const float4*>(baseA + 3 * EMB);
    float4 a3h = *reinterpret_cast<const float4*>(baseA + 3 * EMB + 4);
    __syncthreads();

    {
        f32x4 racc[4] = {};
        #pragma unroll
        for (int kt = 0; kt < 8; ++kt) {
            int kk = kt * 32 + ((lane >> 4) << 3);
            int row = lane & 15;
            bf16x8 a = *reinterpret_cast<const bf16x8*>(qbf + 512 * row + ((kk * 2) ^ ((row & 7) << 4)));
            #pragma unroll
            for (int ntl = 0; ntl < 4; ++ntl) {
                int nt = wave * 4 + ntl;
                bf16x8 b = load_b_tr0(Wr_w, nt * 16 + (lane & 15), kk, TWO_EMB);
                racc[ntl] = __builtin_amdgcn_mfma_f32_16x16x32_bf16(a, b, racc[ntl], 0, 0, 0);
            }
        }
        #pragma unroll
        for (int ntl = 0; ntl < 4; ++ntl) {
            int n = (wave * 4 + ntl) * 16 + (lane & 15);
            #pragma unroll
            for (int i = 0; i < 4; ++i) {
                int row = ((lane >> 4) << 2) + i;
                *reinterpret_cast<unsigned short*>(qrb + row * 1024 + n * 2)
                    = (unsigned short)f2bf_bits(racc[ntl][i]);
            }
        }
    }
    __syncthreads();

    stream_token(baseA, qrb, xz, wave * 2, lane, a0l, a0h, a1l, a1h, a2l, a2h, a3l, a3h);
    {
        float4 b0l = *reinterpret_cast<const float4*>(baseB + 0 * EMB);
        float4 b0h = *reinterpret_cast<const float4*>(baseB + 0 * EMB + 4);
        float4 b1l = *reinterpret_cast<const float4*>(baseB + 1 * EMB);
        float4 b1h = *reinterpret_cast<const float4*>(baseB + 1 * EMB + 4);
        float4 b2l = *reinterpret_cast<const float4*>(baseB + 2 * EMB);
        float4 b2h = *reinterpret_cast<const float4*>(baseB + 2 * EMB + 4);
        float4 b3l = *reinterpret_cast<const float4*>(baseB + 3 * EMB);
        float4 b3h = *reinterpret_cast<const float4*>(baseB + 3 * EMB + 4);
        stream_token(baseB, qrb, xz, wave * 2 + 1, lane, b0l, b0h, b1l, b1h, b2l, b2h, b3l, b3h);
    }
    __syncthreads();

    {
        f32x4 oacc[2] = {};
        #pragma unroll
        for (int kt = 0; kt < 16; ++kt) {
            int kk = kt * 32 + ((lane >> 4) << 3);
            int row = lane & 15;
            bf16x8 a = *reinterpret_cast<const bf16x8*>(xz + 1024 * row + ((kk * 2) ^ ((row & 7) << 4)));
            #pragma unroll
            for (int ntl = 0; ntl < 2; ++ntl) {
                int nt = wave * 2 + ntl;
                bf16x8 b = load_b_rm0(Wv_w, nt * 16 + (lane & 15), kk, TWO_EMB);
                oacc[ntl] = __builtin_amdgcn_mfma_f32_16x16x32_bf16(a, b, oacc[ntl], 0, 0, 0);
            }
        }
        #pragma unroll
        for (int ntl = 0; ntl < 2; ++ntl) {
            int n = (wave * 2 + ntl) * 16 + (lane & 15);
            float bv = Wv_b[n];
            #pragma unroll
            for (int i = 0; i < 4; ++i) {
                int row = ((lane >> 4) << 2) + i;
                unsigned short qu = *reinterpret_cast<const unsigned short*>(
                    qbf + 512 * row + ((n * 2) ^ ((row & 7) << 4)));
                float qv = __builtin_bit_cast(float, (unsigned int)qu << 16);
                out[(long)(tok0 + row) * OUTD + n] = qv + oacc[ntl][i] + bv;
            }
        }
    }
}

extern "C" void kernel_launch(void* const* d_in, const int* in_sizes, int n_in,
                              void* d_out, int out_size, void* d_ws, size_t ws_size,
                              hipStream_t stream) {
    const float* rec  = (const float*)d_in[0];
    const float* pep  = (const float*)d_in[1];
    const float* edge = (const float*)d_in[2];
    const float* Wp_w = (const float*)d_in[3];
    const float* Wp_b = (const float*)d_in[4];
    const float* Wr_w = (const float*)d_in[5];
    // d_in[6] = Wr_b : irrelevant (softmax shift invariance)
    const float* Wv_w = (const float*)d_in[7];
    const float* Wv_b = (const float*)d_in[8];
    float* out = (float*)d_out;

    const size_t m_elems   = 32 * 8 * 64 * 8;    // 131072
    const size_t wpv_elems = 16 * 24 * 64 * 8;   // 196608
    const size_t need = (m_elems + wpv_elems) * sizeof(short) + 512 * sizeof(float);
    short* m_frag   = (short*)d_ws;
    short* wpv_frag = m_frag + m_elems;
    float* c_vec    = (float*)(wpv_frag + wpv_elems);

    if (ws_size >= need) {
        prep_mfrag<<<256, 256, 0, stream>>>(Wr_w, Wp_w, Wp_b, m_frag, c_vec);
        prep_wpv<<<768, 256, 0, stream>>>(Wp_w, Wv_w, wpv_frag);
        ga10_fused<<<N_TOK / T_BLK, THREADS, 0, stream>>>(rec, pep, edge, m_frag, c_vec,
                                                          wpv_frag, Wp_b, Wv_b, out);
    } else {
        ga_fb<<<N_TOK / T_BLK, THREADS, 0, stream>>>(rec, pep, edge, Wp_w, Wp_b, Wr_w,
                                                     Wv_w, Wv_b, out);
    }
}

// Round 13
// 101.951 us; speedup vs baseline: 1.0455x; 1.0455x over previous
//
#include <hip/hip_runtime.h>
#include <hip/hip_bf16.h>

#define N_TOK   16384   // B * N_PEP
#define NREC    10
#define EMB     256
#define TWO_EMB 512
#define OUTD    256
#define T_BLK   32      // tokens per block (2 M-tiles of 16)
#define THREADS 512     // 8 waves; wave w streams tokens 4w..4w+3

typedef __bf16 bf16x8 __attribute__((ext_vector_type(8)));
typedef float  f32x4  __attribute__((ext_vector_type(4)));

static __device__ __forceinline__ unsigned int f2bf_bits(float f) {
    unsigned int u = __builtin_bit_cast(unsigned int, f);
    u = (u + 0x7fffu + ((u >> 16) & 1u)) >> 16;   // RNE bf16
    return u & 0xffffu;
}
static __device__ __forceinline__ unsigned int pack2(float a, float b) {
    return f2bf_bits(a) | (f2bf_bits(b) << 16);
}
static __device__ __forceinline__ float bflo(unsigned int u) {
    return __builtin_bit_cast(float, u << 16);
}
static __device__ __forceinline__ float bfhi(unsigned int u) {
    return __builtin_bit_cast(float, u & 0xffff0000u);
}

// 64-lane sum: 4 DPP row_ror adds + 2 shuffles (validated spill-free, R8/R11).
static __device__ __forceinline__ float wave_sum(float p) {
    p += __builtin_bit_cast(float, __builtin_amdgcn_update_dpp(
             0, __builtin_bit_cast(int, p), 0x121, 0xf, 0xf, true));   // ror1
    p += __builtin_bit_cast(float, __builtin_amdgcn_update_dpp(
             0, __builtin_bit_cast(int, p), 0x122, 0xf, 0xf, true));   // ror2
    p += __builtin_bit_cast(float, __builtin_amdgcn_update_dpp(
             0, __builtin_bit_cast(int, p), 0x124, 0xf, 0xf, true));   // ror4
    p += __builtin_bit_cast(float, __builtin_amdgcn_update_dpp(
             0, __builtin_bit_cast(int, p), 0x128, 0xf, 0xf, true));   // ror8
    p += __shfl_xor(p, 16);
    p += __shfl_xor(p, 32);
    return p;
}

// ---------------- weight fragment prep (bf16, MFMA B-fragment order) ----------
// wp_frag: [16 nt][8 kt][64][8]   q GEMM    B[n=o][k=d] = Wp[n*256+k]
// wr_frag: [32 nt][8 kt][64][8]   qr GEMM   B[n=d][k=o] = Wr[k*512+n]  (transposed use)
// wv_frag: [16 nt][16 kt][64][8]  out GEMM  B[n=o][k=d] = Wv[n*512+k]
__global__ void prep_wfrag(const float* __restrict__ Wp,
                           const float* __restrict__ Wr,
                           const float* __restrict__ Wv,
                           short* __restrict__ wp_frag,
                           short* __restrict__ wr_frag,
                           short* __restrict__ wv_frag) {
    int idx = blockIdx.x * blockDim.x + threadIdx.x;   // grid covers 131072
    if (idx < 16 * 8 * 64 * 8) {
        int j = idx & 7, lane = (idx >> 3) & 63, kt = (idx >> 9) & 7, nt = idx >> 12;
        int n = nt * 16 + (lane & 15), k = kt * 32 + ((lane >> 4) << 3) + j;
        wp_frag[idx] = (short)f2bf_bits(Wp[n * EMB + k]);
    }
    if (idx < 32 * 8 * 64 * 8) {
        int j = idx & 7, lane = (idx >> 3) & 63, kt = (idx >> 9) & 7, nt = idx >> 12;
        int n = nt * 16 + (lane & 15), k = kt * 32 + ((lane >> 4) << 3) + j;
        wr_frag[idx] = (short)f2bf_bits(Wr[k * TWO_EMB + n]);
    }
    if (idx < 16 * 16 * 64 * 8) {
        int j = idx & 7, lane = (idx >> 3) & 63, kt = (idx >> 9) & 15, nt = idx >> 13;
        int n = nt * 16 + (lane & 15), k = kt * 32 + ((lane >> 4) << 3) + j;
        wv_frag[idx] = (short)f2bf_bits(Wv[n * TWO_EMB + k]);
    }
}

// Direct-from-f32 B loaders (fallback path only)
static __device__ __forceinline__ bf16x8 load_b_rm0(const float* __restrict__ W,
                                                    int n, int k, int ld) {
    const float* s = W + (long)n * ld + k;
    float4 f0 = *reinterpret_cast<const float4*>(s);
    float4 f1 = *reinterpret_cast<const float4*>(s + 4);
    uint4 t = { pack2(f0.x, f0.y), pack2(f0.z, f0.w), pack2(f1.x, f1.y), pack2(f1.z, f1.w) };
    return __builtin_bit_cast(bf16x8, t);
}
static __device__ __forceinline__ bf16x8 load_b_tr0(const float* __restrict__ W,
                                                    int n, int k, int ld) {
    unsigned int p[4];
    #pragma unroll
    for (int jj = 0; jj < 4; ++jj)
        p[jj] = pack2(W[(long)(k + 2 * jj) * ld + n], W[(long)(k + 2 * jj + 1) * ld + n]);
    uint4 t = { p[0], p[1], p[2], p[3] };
    return __builtin_bit_cast(bf16x8, t);
}

// ---- one-pass streaming for a token: xbar = (sum e_r x_r) / (sum e_r) --------
// Reads this token's full qr slice into regs FIRST, then writes xbar over the
// SAME LDS slot (in-wave read-before-write; no cross-wave access till barrier).
static __device__ __forceinline__ void stream_token(
    const float* __restrict__ bp,
    const unsigned char* __restrict__ qr_in,   // qr base (linear [t][n*2])
    unsigned char* __restrict__ xz_out,        // xbar base (swizzled A-tile rows)
    int t, int lane,
    float4 s0l, float4 s0h, float4 s1l, float4 s1h,
    float4 s2l, float4 s2h, float4 s3l, float4 s3h)
{
    uint4 qw = *reinterpret_cast<const uint4*>(qr_in + t * 1024 + lane * 16);
    const float qa0 = bflo(qw.x), qa1 = bfhi(qw.x), qa2 = bflo(qw.y), qa3 = bfhi(qw.y);
    const float qa4 = bflo(qw.z), qa5 = bfhi(qw.z), qa6 = bflo(qw.w), qa7 = bfhi(qw.w);
    const float C = 0.0625f * 1.4426950408889634f;   // 1/sqrt(256) * log2(e)

    float s = 0.f;
    float4 xb0 = make_float4(0.f, 0.f, 0.f, 0.f), xb1 = xb0;

    #define LD(r, sl, sh) { sl = *reinterpret_cast<const float4*>(bp + (r) * EMB); \
                            sh = *reinterpret_cast<const float4*>(bp + (r) * EMB + 4); }
    #define PROC(sl, sh) { \
        float p = qa0*(sl).x + qa1*(sl).y + qa2*(sl).z + qa3*(sl).w \
                + qa4*(sh).x + qa5*(sh).y + qa6*(sh).z + qa7*(sh).w; \
        p = wave_sum(p); \
        float e = exp2f(p * C);                      /* no-max: |logit| <~ 2 */ \
        s += e; \
        xb0.x += e*(sl).x; xb0.y += e*(sl).y; xb0.z += e*(sl).z; xb0.w += e*(sl).w; \
        xb1.x += e*(sh).x; xb1.y += e*(sh).y; xb1.z += e*(sh).z; xb1.w += e*(sh).w; }

    PROC(s0l, s0h); LD(4, s0l, s0h);
    PROC(s1l, s1h); LD(5, s1l, s1h);
    PROC(s2l, s2h); LD(6, s2l, s2h);
    PROC(s3l, s3h); LD(7, s3l, s3h);
    PROC(s0l, s0h); LD(8, s0l, s0h);
    PROC(s1l, s1h); LD(9, s1l, s1h);
    PROC(s2l, s2h);
    PROC(s3l, s3h);
    PROC(s0l, s0h);
    PROC(s1l, s1h);
    #undef LD
    #undef PROC

    const float inv = 1.f / s;
    uint4 wv4 = { pack2(xb0.x * inv, xb0.y * inv), pack2(xb0.z * inv, xb0.w * inv),
                  pack2(xb1.x * inv, xb1.y * inv), pack2(xb1.z * inv, xb1.w * inv) };
    *reinterpret_cast<uint4*>(xz_out + 1024 * t + ((lane * 16) ^ ((t & 7) << 4))) = wv4;
}

// ---------------- fused kernel: 32 tokens/block, 2 M-tiles per GEMM -----------
// LDS: pepb 16K + qbf 16K + qrx 32K (qr, overwritten in place by xbar) = 64 KB.
// Each B-fragment load now feeds TWO MFMAs (2 M-tiles) -> L2 frag traffic halved.
template<int USE_FRAG>
__launch_bounds__(THREADS, 4)
__global__ void ga11_fused(const float* __restrict__ rec,
                           const float* __restrict__ pep,
                           const float* __restrict__ edge,
                           const float* __restrict__ Wp_w,
                           const float* __restrict__ Wp_b,
                           const float* __restrict__ Wr_w,
                           const float* __restrict__ Wv_w,
                           const float* __restrict__ Wv_b,
                           const short* __restrict__ wp_frag,
                           const short* __restrict__ wr_frag,
                           const short* __restrict__ wv_frag,
                           float* __restrict__ out) {
    __shared__ __align__(16) unsigned char pepb[T_BLK * 512];    // 16 KB
    __shared__ __align__(16) unsigned char qbf[T_BLK * 512];     // 16 KB
    __shared__ __align__(16) unsigned char qrx[T_BLK * 1024];    // 32 KB (qr -> xbar)

    const int tid  = threadIdx.x;
    const int lane = tid & 63;
    const int wave = tid >> 6;
    const int tok0 = blockIdx.x * T_BLK;

    // ---- stage pep tile as bf16 (swizzled): 32 rows x 64 float4 ----
    #pragma unroll
    for (int it = 0; it < 4; ++it) {
        int idx = tid + it * THREADS;
        int row = idx >> 6, d4 = (idx & 63) << 2;
        float4 f = *reinterpret_cast<const float4*>(pep + (long)(tok0 + row) * EMB + d4);
        uint2 w = { pack2(f.x, f.y), pack2(f.z, f.w) };
        *reinterpret_cast<uint2*>(pepb + 512 * row + ((d4 * 2) ^ ((row & 7) << 4))) = w;
    }
    __syncthreads();                            // B1: pep tile ready

    // ---- 1a: q = pep @ Wp^T + bp  (M=32,K=256,N=256; 2 nt/wave x 2 mtiles) ----
    {
        f32x4 qacc[2][2] = {};
        #pragma unroll
        for (int kt = 0; kt < 8; ++kt) {
            int kk = kt * 32 + ((lane >> 4) << 3);
            int r0 = lane & 15, r1 = 16 + r0;
            bf16x8 a0 = *reinterpret_cast<const bf16x8*>(pepb + 512 * r0 + ((kk * 2) ^ ((r0 & 7) << 4)));
            bf16x8 a1 = *reinterpret_cast<const bf16x8*>(pepb + 512 * r1 + ((kk * 2) ^ ((r1 & 7) << 4)));
            #pragma unroll
            for (int ntl = 0; ntl < 2; ++ntl) {
                int nt = wave * 2 + ntl;
                bf16x8 b;
                if constexpr (USE_FRAG) b = *reinterpret_cast<const bf16x8*>(wp_frag + (((nt * 8 + kt) * 64 + lane) << 3));
                else                    b = load_b_rm0(Wp_w, nt * 16 + (lane & 15), kk, EMB);
                qacc[0][ntl] = __builtin_amdgcn_mfma_f32_16x16x32_bf16(a0, b, qacc[0][ntl], 0, 0, 0);
                qacc[1][ntl] = __builtin_amdgcn_mfma_f32_16x16x32_bf16(a1, b, qacc[1][ntl], 0, 0, 0);
            }
        }
        #pragma unroll
        for (int mt = 0; mt < 2; ++mt) {
            #pragma unroll
            for (int ntl = 0; ntl < 2; ++ntl) {
                int n = (wave * 2 + ntl) * 16 + (lane & 15);
                float bias = Wp_b[n];
                #pragma unroll
                for (int i = 0; i < 4; ++i) {
                    int row = mt * 16 + ((lane >> 4) << 2) + i;
                    *reinterpret_cast<unsigned short*>(qbf + 512 * row + ((n * 2) ^ ((row & 7) << 4)))
                        = (unsigned short)f2bf_bits(qacc[mt][ntl][i] + bias);
                }
            }
        }
    }

    // ---- pre-issue ring of first streamed token (rows 0..3) ----
    const float* srcA = (lane < 32) ? rec : edge;
    const int dloc = (lane * 8) & 255;
    const float* base0 = srcA + (long)(tok0 + wave * 4) * NREC * EMB + dloc;
    float4 a0l = *reinterpret_cast<const float4*>(base0 + 0 * EMB);
    float4 a0h = *reinterpret_cast<const float4*>(base0 + 0 * EMB + 4);
    float4 a1l = *reinterpret_cast<const float4*>(base0 + 1 * EMB);
    float4 a1h = *reinterpret_cast<const float4*>(base0 + 1 * EMB + 4);
    float4 a2l = *reinterpret_cast<const float4*>(base0 + 2 * EMB);
    float4 a2h = *reinterpret_cast<const float4*>(base0 + 2 * EMB + 4);
    float4 a3l = *reinterpret_cast<const float4*>(base0 + 3 * EMB);
    float4 a3h = *reinterpret_cast<const float4*>(base0 + 3 * EMB + 4);
    __syncthreads();                            // B2: qbf ready

    // ---- 1b: qr = q @ Wr  (M=32,K=256,N=512; 4 nt/wave x 2 mtiles) ----
    {
        f32x4 racc[2][4] = {};
        #pragma unroll
        for (int kt = 0; kt < 8; ++kt) {
            int kk = kt * 32 + ((lane >> 4) << 3);
            int r0 = lane & 15, r1 = 16 + r0;
            bf16x8 a0 = *reinterpret_cast<const bf16x8*>(qbf + 512 * r0 + ((kk * 2) ^ ((r0 & 7) << 4)));
            bf16x8 a1 = *reinterpret_cast<const bf16x8*>(qbf + 512 * r1 + ((kk * 2) ^ ((r1 & 7) << 4)));
            #pragma unroll
            for (int ntl = 0; ntl < 4; ++ntl) {
                int nt = wave * 4 + ntl;
                bf16x8 b;
                if constexpr (USE_FRAG) b = *reinterpret_cast<const bf16x8*>(wr_frag + (((nt * 8 + kt) * 64 + lane) << 3));
                else                    b = load_b_tr0(Wr_w, nt * 16 + (lane & 15), kk, TWO_EMB);
                racc[0][ntl] = __builtin_amdgcn_mfma_f32_16x16x32_bf16(a0, b, racc[0][ntl], 0, 0, 0);
                racc[1][ntl] = __builtin_amdgcn_mfma_f32_16x16x32_bf16(a1, b, racc[1][ntl], 0, 0, 0);
            }
        }
        #pragma unroll
        for (int mt = 0; mt < 2; ++mt) {
            #pragma unroll
            for (int ntl = 0; ntl < 4; ++ntl) {
                int n = (wave * 4 + ntl) * 16 + (lane & 15);
                #pragma unroll
                for (int i = 0; i < 4; ++i) {
                    int row = mt * 16 + ((lane >> 4) << 2) + i;
                    *reinterpret_cast<unsigned short*>(qrx + row * 1024 + n * 2)
                        = (unsigned short)f2bf_bits(racc[mt][ntl][i]);
                }
            }
        }
    }
    __syncthreads();                            // B3: qr ready

    // ---- streaming: 4 tokens/wave; xbar overwrites qr slot in place ----
    {
        const int t0 = wave * 4;
        stream_token(base0, qrx, qrx, t0, lane, a0l, a0h, a1l, a1h, a2l, a2h, a3l, a3h);
        #pragma unroll
        for (int k = 1; k < 4; ++k) {
            const float* bp = base0 + (long)k * NREC * EMB;
            float4 b0l = *reinterpret_cast<const float4*>(bp + 0 * EMB);
            float4 b0h = *reinterpret_cast<const float4*>(bp + 0 * EMB + 4);
            float4 b1l = *reinterpret_cast<const float4*>(bp + 1 * EMB);
            float4 b1h = *reinterpret_cast<const float4*>(bp + 1 * EMB + 4);
            float4 b2l = *reinterpret_cast<const float4*>(bp + 2 * EMB);
            float4 b2h = *reinterpret_cast<const float4*>(bp + 2 * EMB + 4);
            float4 b3l = *reinterpret_cast<const float4*>(bp + 3 * EMB);
            float4 b3h = *reinterpret_cast<const float4*>(bp + 3 * EMB + 4);
            stream_token(bp, qrx, qrx, t0 + k, lane, b0l, b0h, b1l, b1h, b2l, b2h, b3l, b3h);
        }
    }
    __syncthreads();                            // B4: xbar tile ready

    // ---- ph3: out = q + Wv @ xbar + bv  (M=32,K=512,N=256; 2 nt x 2 mtiles) ----
    {
        f32x4 oacc[2][2] = {};
        #pragma unroll
        for (int kt = 0; kt < 16; ++kt) {
            int kk = kt * 32 + ((lane >> 4) << 3);
            int r0 = lane & 15, r1 = 16 + r0;
            bf16x8 a0 = *reinterpret_cast<const bf16x8*>(qrx + 1024 * r0 + ((kk * 2) ^ ((r0 & 7) << 4)));
            bf16x8 a1 = *reinterpret_cast<const bf16x8*>(qrx + 1024 * r1 + ((kk * 2) ^ ((r1 & 7) << 4)));
            #pragma unroll
            for (int ntl = 0; ntl < 2; ++ntl) {
                int nt = wave * 2 + ntl;
                bf16x8 b;
                if constexpr (USE_FRAG) b = *reinterpret_cast<const bf16x8*>(wv_frag + (((nt * 16 + kt) * 64 + lane) << 3));
                else                    b = load_b_rm0(Wv_w, nt * 16 + (lane & 15), kk, TWO_EMB);
                oacc[0][ntl] = __builtin_amdgcn_mfma_f32_16x16x32_bf16(a0, b, oacc[0][ntl], 0, 0, 0);
                oacc[1][ntl] = __builtin_amdgcn_mfma_f32_16x16x32_bf16(a1, b, oacc[1][ntl], 0, 0, 0);
            }
        }
        #pragma unroll
        for (int mt = 0; mt < 2; ++mt) {
            #pragma unroll
            for (int ntl = 0; ntl < 2; ++ntl) {
                int n = (wave * 2 + ntl) * 16 + (lane & 15);
                float bv = Wv_b[n];
                #pragma unroll
                for (int i = 0; i < 4; ++i) {
                    int row = mt * 16 + ((lane >> 4) << 2) + i;
                    unsigned short qu = *reinterpret_cast<const unsigned short*>(
                        qbf + 512 * row + ((n * 2) ^ ((row & 7) << 4)));
                    float qv = __builtin_bit_cast(float, (unsigned int)qu << 16);
                    out[(long)(tok0 + row) * OUTD + n] = qv + oacc[mt][ntl][i] + bv;
                }
            }
        }
    }
}

extern "C" void kernel_launch(void* const* d_in, const int* in_sizes, int n_in,
                              void* d_out, int out_size, void* d_ws, size_t ws_size,
                              hipStream_t stream) {
    const float* rec  = (const float*)d_in[0];
    const float* pep  = (const float*)d_in[1];
    const float* edge = (const float*)d_in[2];
    const float* Wp_w = (const float*)d_in[3];
    const float* Wp_b = (const float*)d_in[4];
    const float* Wr_w = (const float*)d_in[5];
    // d_in[6] = Wr_b : irrelevant (softmax shift invariance)
    const float* Wv_w = (const float*)d_in[7];
    const float* Wv_b = (const float*)d_in[8];
    float* out = (float*)d_out;

    const size_t wp_elems = 16 * 8 * 64 * 8;    // 65536
    const size_t wr_elems = 32 * 8 * 64 * 8;    // 131072
    const size_t wv_elems = 16 * 16 * 64 * 8;   // 131072
    const size_t need = (wp_elems + wr_elems + wv_elems) * sizeof(short);
    short* wp_frag = (short*)d_ws;
    short* wr_frag = wp_frag + wp_elems;
    short* wv_frag = wr_frag + wr_elems;

    if (ws_size >= need) {
        prep_wfrag<<<512, 256, 0, stream>>>(Wp_w, Wr_w, Wv_w, wp_frag, wr_frag, wv_frag);
        ga11_fused<1><<<N_TOK / T_BLK, THREADS, 0, stream>>>(rec, pep, edge, Wp_w, Wp_b, Wr_w,
                                                             Wv_w, Wv_b, wp_frag, wr_frag, wv_frag, out);
    } else {
        ga11_fused<0><<<N_TOK / T_BLK, THREADS, 0, stream>>>(rec, pep, edge, Wp_w, Wp_b, Wr_w,
                                                             Wv_w, Wv_b, wp_frag, wr_frag, wv_frag, out);
    }
}

// Round 14
// 99.277 us; speedup vs baseline: 1.0737x; 1.0269x over previous
//
#include <hip/hip_runtime.h>
#include <hip/hip_bf16.h>

#define N_TOK   16384   // B * N_PEP
#define NREC    10
#define EMB     256
#define TWO_EMB 512
#define OUTD    256
#define T_BLK   16      // tokens per block
#define THREADS 512     // 8 waves; wave w owns tokens 2w, 2w+1 in streaming phase

typedef __bf16 bf16x8 __attribute__((ext_vector_type(8)));
typedef float  f32x4  __attribute__((ext_vector_type(4)));

static __device__ __forceinline__ unsigned int f2bf_bits(float f) {
    unsigned int u = __builtin_bit_cast(unsigned int, f);
    u = (u + 0x7fffu + ((u >> 16) & 1u)) >> 16;   // RNE bf16
    return u & 0xffffu;
}
static __device__ __forceinline__ unsigned int pack2(float a, float b) {
    return f2bf_bits(a) | (f2bf_bits(b) << 16);
}
static __device__ __forceinline__ float bflo(unsigned int u) {
    return __builtin_bit_cast(float, u << 16);
}
static __device__ __forceinline__ float bfhi(unsigned int u) {
    return __builtin_bit_cast(float, u & 0xffff0000u);
}

// 64-lane sum: 4 DPP row_ror adds + 2 shuffles (validated spill-free, R8/R11).
static __device__ __forceinline__ float wave_sum(float p) {
    p += __builtin_bit_cast(float, __builtin_amdgcn_update_dpp(
             0, __builtin_bit_cast(int, p), 0x121, 0xf, 0xf, true));   // ror1
    p += __builtin_bit_cast(float, __builtin_amdgcn_update_dpp(
             0, __builtin_bit_cast(int, p), 0x122, 0xf, 0xf, true));   // ror2
    p += __builtin_bit_cast(float, __builtin_amdgcn_update_dpp(
             0, __builtin_bit_cast(int, p), 0x124, 0xf, 0xf, true));   // ror4
    p += __builtin_bit_cast(float, __builtin_amdgcn_update_dpp(
             0, __builtin_bit_cast(int, p), 0x128, 0xf, 0xf, true));   // ror8
    p += __shfl_xor(p, 16);
    p += __shfl_xor(p, 32);
    return p;
}

// ---------------- weight fragment prep (bf16, MFMA B-fragment order) ----------
// wp_frag: [16 nt][8 kt][64][8]   q GEMM    B[n=o][k=d] = Wp[n*256+k]
// wr_frag: [32 nt][8 kt][64][8]   qr GEMM   B[n=d][k=o] = Wr[k*512+n]  (transposed use)
// wv_frag: [16 nt][16 kt][64][8]  out GEMM  B[n=o][k=d] = Wv[n*512+k]
__global__ void prep_wfrag(const float* __restrict__ Wp,
                           const float* __restrict__ Wr,
                           const float* __restrict__ Wv,
                           short* __restrict__ wp_frag,
                           short* __restrict__ wr_frag,
                           short* __restrict__ wv_frag) {
    int idx = blockIdx.x * blockDim.x + threadIdx.x;   // grid covers 131072
    if (idx < 16 * 8 * 64 * 8) {
        int j = idx & 7, lane = (idx >> 3) & 63, kt = (idx >> 9) & 7, nt = idx >> 12;
        int n = nt * 16 + (lane & 15), k = kt * 32 + ((lane >> 4) << 3) + j;
        wp_frag[idx] = (short)f2bf_bits(Wp[n * EMB + k]);
    }
    if (idx < 32 * 8 * 64 * 8) {
        int j = idx & 7, lane = (idx >> 3) & 63, kt = (idx >> 9) & 7, nt = idx >> 12;
        int n = nt * 16 + (lane & 15), k = kt * 32 + ((lane >> 4) << 3) + j;
        wr_frag[idx] = (short)f2bf_bits(Wr[k * TWO_EMB + n]);
    }
    if (idx < 16 * 16 * 64 * 8) {
        int j = idx & 7, lane = (idx >> 3) & 63, kt = (idx >> 9) & 15, nt = idx >> 13;
        int n = nt * 16 + (lane & 15), k = kt * 32 + ((lane >> 4) << 3) + j;
        wv_frag[idx] = (short)f2bf_bits(Wv[n * TWO_EMB + k]);
    }
}

// B-fragment loaders (frag path or direct-from-f32 fallback)
template<int USE_FRAG>
static __device__ __forceinline__ bf16x8 load_b_rm(const short* __restrict__ frag,
                                                   const float* __restrict__ W,
                                                   int n, int k, int ld) {
    if constexpr (USE_FRAG) {
        return *reinterpret_cast<const bf16x8*>(frag);
    } else {
        const float* s = W + (long)n * ld + k;
        float4 f0 = *reinterpret_cast<const float4*>(s);
        float4 f1 = *reinterpret_cast<const float4*>(s + 4);
        uint4 t = { pack2(f0.x, f0.y), pack2(f0.z, f0.w), pack2(f1.x, f1.y), pack2(f1.z, f1.w) };
        return __builtin_bit_cast(bf16x8, t);
    }
}
template<int USE_FRAG>
static __device__ __forceinline__ bf16x8 load_b_tr(const short* __restrict__ frag,
                                                   const float* __restrict__ W,
                                                   int n, int k, int ld) {
    if constexpr (USE_FRAG) {
        return *reinterpret_cast<const bf16x8*>(frag);
    } else {
        unsigned int p[4];
        #pragma unroll
        for (int jj = 0; jj < 4; ++jj)
            p[jj] = pack2(W[(long)(k + 2 * jj) * ld + n], W[(long)(k + 2 * jj + 1) * ld + n]);
        uint4 t = { p[0], p[1], p[2], p[3] };
        return __builtin_bit_cast(bf16x8, t);
    }
}

// ---- one-pass streaming, ring-4, chained across tokens -----------------------
// Slots (s0..s3) hold rows 0..3 of bp on entry. If HAS_NEXT, rows 6-9's PROCs
// refill slots with bpn rows 0..3; exit order is (s2,s3,s0,s1) = next rows 0..3,
// so the caller passes rotated refs on the next call (R8-validated pattern).
template<int HAS_NEXT>
static __device__ __forceinline__ void stream_token(
    const float* __restrict__ bp, const float* __restrict__ bpn,
    const unsigned char* __restrict__ qrb, unsigned char* __restrict__ xz,
    int t, int lane,
    float4& s0l, float4& s0h, float4& s1l, float4& s1h,
    float4& s2l, float4& s2h, float4& s3l, float4& s3h)
{
    uint4 qw = *reinterpret_cast<const uint4*>(qrb + t * 1024 + lane * 16);
    const float qa0 = bflo(qw.x), qa1 = bfhi(qw.x), qa2 = bflo(qw.y), qa3 = bfhi(qw.y);
    const float qa4 = bflo(qw.z), qa5 = bfhi(qw.z), qa6 = bflo(qw.w), qa7 = bfhi(qw.w);
    const float C = 0.0625f * 1.4426950408889634f;   // 1/sqrt(256) * log2(e)

    float s = 0.f;
    float4 xb0 = make_float4(0.f, 0.f, 0.f, 0.f), xb1 = xb0;

    #define LD(base, r, sl, sh) { \
        sl = *reinterpret_cast<const float4*>((base) + (r) * EMB); \
        sh = *reinterpret_cast<const float4*>((base) + (r) * EMB + 4); }
    #define PROC(sl, sh) { \
        float p = qa0*(sl).x + qa1*(sl).y + qa2*(sl).z + qa3*(sl).w \
                + qa4*(sh).x + qa5*(sh).y + qa6*(sh).z + qa7*(sh).w; \
        p = wave_sum(p); \
        float e = exp2f(p * C);                      /* no-max: |logit| <~ 2 */ \
        s += e; \
        xb0.x += e*(sl).x; xb0.y += e*(sl).y; xb0.z += e*(sl).z; xb0.w += e*(sl).w; \
        xb1.x += e*(sh).x; xb1.y += e*(sh).y; xb1.z += e*(sh).z; xb1.w += e*(sh).w; }

    PROC(s0l, s0h); LD(bp, 4, s0l, s0h);
    PROC(s1l, s1h); LD(bp, 5, s1l, s1h);
    PROC(s2l, s2h); LD(bp, 6, s2l, s2h);
    PROC(s3l, s3h); LD(bp, 7, s3l, s3h);
    PROC(s0l, s0h); LD(bp, 8, s0l, s0h);
    PROC(s1l, s1h); LD(bp, 9, s1l, s1h);
    PROC(s2l, s2h); if (HAS_NEXT) LD(bpn, 0, s2l, s2h);
    PROC(s3l, s3h); if (HAS_NEXT) LD(bpn, 1, s3l, s3h);
    PROC(s0l, s0h); if (HAS_NEXT) LD(bpn, 2, s0l, s0h);
    PROC(s1l, s1h); if (HAS_NEXT) LD(bpn, 3, s1l, s1h);
    #undef LD
    #undef PROC

    const float inv = 1.f / s;
    uint4 wv4 = { pack2(xb0.x * inv, xb0.y * inv), pack2(xb0.z * inv, xb0.w * inv),
                  pack2(xb1.x * inv, xb1.y * inv), pack2(xb1.z * inv, xb1.w * inv) };
    *reinterpret_cast<uint4*>(xz + 1024 * t + ((lane * 16) ^ ((t & 7) << 4))) = wv4;
}

// ---------------- fused kernel (commuted-projection formulation) --------------
// per token t:  q  = Wp@pep + bp                      (MFMA; kept in qbf as bf16)
//               qr = Wr^T q                           (MFMA; Wr_b drops: softmax shift-inv)
//               e_r = exp((qr . x_r)/16)              (streamed f32, one pass)
//               xbar = (sum e_r x_r) / (sum e_r)
//               out = q + Wv@xbar + bv                (MFMA; sum(attn)=1 folds bias)
template<int USE_FRAG>
__launch_bounds__(THREADS, 4)
__global__ void ga12_fused(const float* __restrict__ rec,
                           const float* __restrict__ pep,
                           const float* __restrict__ edge,
                           const float* __restrict__ Wp_w,
                           const float* __restrict__ Wp_b,
                           const float* __restrict__ Wr_w,
                           const float* __restrict__ Wv_w,
                           const float* __restrict__ Wv_b,
                           const short* __restrict__ wp_frag,
                           const short* __restrict__ wr_frag,
                           const short* __restrict__ wv_frag,
                           float* __restrict__ out) {
    // xz: pep bf16 A-tile (512B rows) in 1a, then xbar bf16 A-tile (1024B rows) in ph3
    __shared__ __align__(16) unsigned char xz[T_BLK * 1024];       // 16 KB
    __shared__ __align__(16) unsigned char qbf[T_BLK * 512];       // 8 KB (q bf16 A-tile)
    __shared__ __align__(16) unsigned char qrb[T_BLK * 1024];      // 16 KB (qr bf16 [t][512])

    const int tid  = threadIdx.x;
    const int lane = tid & 63;
    const int wave = tid >> 6;
    const int tok0 = blockIdx.x * T_BLK;

    // ---- ring pre-issue at kernel ENTRY: token-A rows 0..3 (independent of
    // everything; latency hides under staging + 1a + 1b) ----
    const float* srcA = (lane < 32) ? rec : edge;
    const int dloc = (lane * 8) & 255;
    const float* baseA = srcA + (long)(tok0 + wave * 2) * NREC * EMB + dloc;
    const float* baseB = baseA + (long)NREC * EMB;   // token A+1
    float4 a0l = *reinterpret_cast<const float4*>(baseA + 0 * EMB);
    float4 a0h = *reinterpret_cast<const float4*>(baseA + 0 * EMB + 4);
    float4 a1l = *reinterpret_cast<const float4*>(baseA + 1 * EMB);
    float4 a1h = *reinterpret_cast<const float4*>(baseA + 1 * EMB + 4);
    float4 a2l = *reinterpret_cast<const float4*>(baseA + 2 * EMB);
    float4 a2h = *reinterpret_cast<const float4*>(baseA + 2 * EMB + 4);
    float4 a3l = *reinterpret_cast<const float4*>(baseA + 3 * EMB);
    float4 a3h = *reinterpret_cast<const float4*>(baseA + 3 * EMB + 4);

    // ---- stage pep tile as bf16 (swizzled) ----
    #pragma unroll
    for (int it = 0; it < 2; ++it) {
        int idx = tid + it * THREADS;          // 16 rows x 64 float4
        int row = idx >> 6, d4 = (idx & 63) << 2;
        float4 f = *reinterpret_cast<const float4*>(pep + (long)(tok0 + row) * EMB + d4);
        uint2 w = { pack2(f.x, f.y), pack2(f.z, f.w) };
        *reinterpret_cast<uint2*>(xz + 512 * row + ((d4 * 2) ^ ((row & 7) << 4))) = w;
    }
    __syncthreads();                            // B1: pep tile ready

    // ---- 1a: q = pep @ Wp^T + bp  (M=16,K=256,N=256; 2 n-tiles/wave) ----
    {
        f32x4 qacc[2] = {};
        #pragma unroll
        for (int kt = 0; kt < 8; ++kt) {
            int kk = kt * 32 + ((lane >> 4) << 3);
            int row = lane & 15;
            bf16x8 a = *reinterpret_cast<const bf16x8*>(xz + 512 * row + ((kk * 2) ^ ((row & 7) << 4)));
            #pragma unroll
            for (int ntl = 0; ntl < 2; ++ntl) {
                int nt = wave * 2 + ntl;
                bf16x8 b = load_b_rm<USE_FRAG>(wp_frag + ((nt * 8 + kt) * 64 + lane) * 8,
                                               Wp_w, nt * 16 + (lane & 15), kk, EMB);
                qacc[ntl] = __builtin_amdgcn_mfma_f32_16x16x32_bf16(a, b, qacc[ntl], 0, 0, 0);
            }
        }
        #pragma unroll
        for (int ntl = 0; ntl < 2; ++ntl) {
            int n = (wave * 2 + ntl) * 16 + (lane & 15);
            float bias = Wp_b[n];
            #pragma unroll
            for (int i = 0; i < 4; ++i) {
                int row = ((lane >> 4) << 2) + i;
                float v = qacc[ntl][i] + bias;
                *reinterpret_cast<unsigned short*>(qbf + 512 * row + ((n * 2) ^ ((row & 7) << 4)))
                    = (unsigned short)f2bf_bits(v);
            }
        }
    }
    __syncthreads();                            // B2: qbf ready

    // ---- 1b: qr = q @ Wr  (M=16,K=256,N=512; 4 n-tiles/wave), stored bf16 ----
    {
        f32x4 racc[4] = {};
        #pragma unroll
        for (int kt = 0; kt < 8; ++kt) {
            int kk = kt * 32 + ((lane >> 4) << 3);
            int row = lane & 15;
            bf16x8 a = *reinterpret_cast<const bf16x8*>(qbf + 512 * row + ((kk * 2) ^ ((row & 7) << 4)));
            #pragma unroll
            for (int ntl = 0; ntl < 4; ++ntl) {
                int nt = wave * 4 + ntl;
                bf16x8 b = load_b_tr<USE_FRAG>(wr_frag + ((nt * 8 + kt) * 64 + lane) * 8,
                                               Wr_w, nt * 16 + (lane & 15), kk, TWO_EMB);
                racc[ntl] = __builtin_amdgcn_mfma_f32_16x16x32_bf16(a, b, racc[ntl], 0, 0, 0);
            }
        }
        #pragma unroll
        for (int ntl = 0; ntl < 4; ++ntl) {
            int n = (wave * 4 + ntl) * 16 + (lane & 15);
            #pragma unroll
            for (int i = 0; i < 4; ++i) {
                int row = ((lane >> 4) << 2) + i;
                *reinterpret_cast<unsigned short*>(qrb + row * 1024 + n * 2)
                    = (unsigned short)f2bf_bits(racc[ntl][i]);
            }
        }
    }
    __syncthreads();                            // B3: qrb ready

    // ---- streaming: token A chains into token B (no boundary stall) ----
    stream_token<1>(baseA, baseB, qrb, xz, wave * 2, lane,
                    a0l, a0h, a1l, a1h, a2l, a2h, a3l, a3h);
    stream_token<0>(baseB, baseB, qrb, xz, wave * 2 + 1, lane,
                    a2l, a2h, a3l, a3h, a0l, a0h, a1l, a1h);   // rotated slot refs
    __syncthreads();                            // B4: xbar tile ready

    // ---- ph3: out = q + Wv @ xbar + bv  (M=16,K=512,N=256; 2 n-tiles/wave) ----
    {
        f32x4 oacc[2] = {};
        #pragma unroll
        for (int kt = 0; kt < 16; ++kt) {
            int kk = kt * 32 + ((lane >> 4) << 3);
            int row = lane & 15;
            bf16x8 a = *reinterpret_cast<const bf16x8*>(xz + 1024 * row + ((kk * 2) ^ ((row & 7) << 4)));
            #pragma unroll
            for (int ntl = 0; ntl < 2; ++ntl) {
                int nt = wave * 2 + ntl;
                bf16x8 b = load_b_rm<USE_FRAG>(wv_frag + ((nt * 16 + kt) * 64 + lane) * 8,
                                               Wv_w, nt * 16 + (lane & 15), kk, TWO_EMB);
                oacc[ntl] = __builtin_amdgcn_mfma_f32_16x16x32_bf16(a, b, oacc[ntl], 0, 0, 0);
            }
        }
        #pragma unroll
        for (int ntl = 0; ntl < 2; ++ntl) {
            int n = (wave * 2 + ntl) * 16 + (lane & 15);
            float bv = Wv_b[n];
            #pragma unroll
            for (int i = 0; i < 4; ++i) {
                int row = ((lane >> 4) << 2) + i;
                unsigned short qu = *reinterpret_cast<const unsigned short*>(
                    qbf + 512 * row + ((n * 2) ^ ((row & 7) << 4)));
                float qv = __builtin_bit_cast(float, (unsigned int)qu << 16);
                out[(long)(tok0 + row) * OUTD + n] = qv + oacc[ntl][i] + bv;
            }
        }
    }
}

extern "C" void kernel_launch(void* const* d_in, const int* in_sizes, int n_in,
                              void* d_out, int out_size, void* d_ws, size_t ws_size,
                              hipStream_t stream) {
    const float* rec  = (const float*)d_in[0];
    const float* pep  = (const float*)d_in[1];
    const float* edge = (const float*)d_in[2];
    const float* Wp_w = (const float*)d_in[3];
    const float* Wp_b = (const float*)d_in[4];
    const float* Wr_w = (const float*)d_in[5];
    // d_in[6] = Wr_b : irrelevant (softmax shift invariance)
    const float* Wv_w = (const float*)d_in[7];
    const float* Wv_b = (const float*)d_in[8];
    float* out = (float*)d_out;

    const size_t wp_elems = 16 * 8 * 64 * 8;    // 65536
    const size_t wr_elems = 32 * 8 * 64 * 8;    // 131072
    const size_t wv_elems = 16 * 16 * 64 * 8;   // 131072
    const size_t need = (wp_elems + wr_elems + wv_elems) * sizeof(short);
    short* wp_frag = (short*)d_ws;
    short* wr_frag = wp_frag + wp_elems;
    short* wv_frag = wr_frag + wr_elems;

    if (ws_size >= need) {
        prep_wfrag<<<512, 256, 0, stream>>>(Wp_w, Wr_w, Wv_w, wp_frag, wr_frag, wv_frag);
        ga12_fused<1><<<N_TOK / T_BLK, THREADS, 0, stream>>>(rec, pep, edge, Wp_w, Wp_b, Wr_w,
                                                             Wv_w, Wv_b, wp_frag, wr_frag, wv_frag, out);
    } else {
        ga12_fused<0><<<N_TOK / T_BLK, THREADS, 0, stream>>>(rec, pep, edge, Wp_w, Wp_b, Wr_w,
                                                             Wv_w, Wv_b, wp_frag, wr_frag, wv_frag, out);
    }
}